// Round 12
// baseline (656.555 us; speedup 1.0000x reference)
//
#include <hip/hip_runtime.h>

#define B_TOK 32768
#define EDIM 2048
#define RDIM 128
#define NEXP 16
#define BK 128          // K-chunk (floats)
#define XPITCH 33       // float4 pitch per x row in LDS (132 floats)

// ---------------------------------------------------------------------------
// Kernel 1: router logits (double acc) + argmax + atomic append to per-expert
// token lists. perm layout: perm[e * B_TOK + slot] = token.  UNCHANGED (passed).
// ---------------------------------------------------------------------------
__global__ __launch_bounds__(256) void k_router(
    const float* __restrict__ rin, const float* __restrict__ rw,
    const float* __restrict__ rb, int* __restrict__ counts,
    int* __restrict__ perm)
{
  __shared__ float lds[64 * 132];
  const int t = threadIdx.x;
  const int row0 = blockIdx.x * 64;

  {
    const int r = t >> 2;
    const int c0 = t & 3;
    const float4* src = (const float4*)(rin + (size_t)(row0 + r) * RDIM);
    float4* dst = (float4*)lds;
#pragma unroll
    for (int j = 0; j < 8; ++j) {
      const int f4 = c0 + 4 * j;
      dst[r * 33 + f4] = src[f4];
    }
  }
  __syncthreads();

  if (t < 64) {
    const int token = row0 + t;
    const float4* arow = (const float4*)lds + t * 33;
    double best = -1e300;
    int bi = 0;
#pragma unroll 1
    for (int e = 0; e < NEXP; ++e) {
      const float4* w = (const float4*)(rw + e * RDIM);
      double s = (double)rb[e];
#pragma unroll
      for (int i4 = 0; i4 < 32; ++i4) {
        const float4 a = arow[i4];
        const float4 ww = w[i4];
        s += (double)a.x * ww.x + (double)a.y * ww.y +
             (double)a.z * ww.z + (double)a.w * ww.w;
      }
      if (s > best) { best = s; bi = e; }
    }
    const int slot = atomicAdd(&counts[bi], 1);
    perm[bi * B_TOK + slot] = token;
  }
}

// ---------------------------------------------------------------------------
// Kernel 2: per-expert fused l1 (2048->16) + act + l2 (30->32) + out (32->1)
// + residual. Block = 64 tokens of ONE expert, 256 threads, 3 blocks/CU.
//  - w1 K-chunk staged in LDS (no global loads in the hot loop)
//  - x staged with 512B-contiguous runs (32 lanes per row)
// ---------------------------------------------------------------------------
__global__ __launch_bounds__(256, 3) void k_moe(
    const float* __restrict__ xin, const float* __restrict__ w1,
    const float* __restrict__ b1, const float* __restrict__ w2,
    const float* __restrict__ b2, const float* __restrict__ w3,
    const float* __restrict__ b3, const int* __restrict__ counts,
    const int* __restrict__ perm, float* __restrict__ out)
{
  const int e = blockIdx.y;
  const int n = counts[e];
  const int start = blockIdx.x * 64;
  if (start >= n) return;

  const int t = threadIdx.x;
  __shared__ float4 x_lds[64 * XPITCH];   // 33792 B
  __shared__ float4 w_lds[16 * 32];       // 8192 B : [o][i4] for current chunk
  __shared__ float  c_lds[64 * 17];       // 4352 B : l1c per token
  __shared__ int    tok_lds[64];

  if (t < 64) {
    const int idx = start + t;
    tok_lds[t] = (idx < n) ? perm[e * B_TOK + idx] : 0;  // 0 = safe dummy row
  }
  __syncthreads();

  // staging roles: 32 lanes per row -> 512B contiguous runs
  const int srow  = t >> 5;   // 0..7
  const int slane = t & 31;   // f4 index within the 512B chunk-row
  // compute roles
  const int m  = t & 63;                                  // token within block
  const int og = __builtin_amdgcn_readfirstlane(t >> 6);  // 0..3, wave-uniform

  // prefetch the 8 source-row pointers this thread stages (static unroll)
  const float* srcp[8];
#pragma unroll
  for (int rr = 0; rr < 8; ++rr)
    srcp[rr] = xin + (size_t)tok_lds[srow + 8 * rr] * EDIM;

  const float4* w1e = (const float4*)(w1 + (size_t)e * 16 * EDIM);

  float acc0 = 0.f, acc1 = 0.f, acc2 = 0.f, acc3 = 0.f;

  for (int kc = 0; kc < EDIM; kc += BK) {
    __syncthreads();   // previous chunk's readers done
    // --- stage x: 8 rounds x 8 rows, 512B contiguous per row ---
#pragma unroll
    for (int rr = 0; rr < 8; ++rr) {
      const int row = srow + 8 * rr;
      x_lds[row * XPITCH + slane] =
          ((const float4*)(srcp[rr] + kc))[slane];
    }
    // --- stage w1 chunk: 16 outputs x 32 f4 = 512 f4, 2 per thread ---
#pragma unroll
    for (int q = 0; q < 2; ++q) {
      const int idx = q * 256 + t;
      const int o  = idx >> 5;
      const int i4 = idx & 31;
      w_lds[o * 32 + i4] = w1e[(size_t)o * (EDIM / 4) + (kc / 4) + i4];
    }
    __syncthreads();

    // --- compute: 4 outputs per thread, weights via LDS broadcast ---
    const float4* xr = &x_lds[m * XPITCH];
    const float4* wr = &w_lds[og * 4 * 32];
#pragma unroll
    for (int i4 = 0; i4 < 32; ++i4) {
      const float4 a  = xr[i4];
      const float4 q0 = wr[i4];
      const float4 q1 = wr[32 + i4];
      const float4 q2 = wr[64 + i4];
      const float4 q3 = wr[96 + i4];
      acc0 = fmaf(a.x, q0.x, acc0); acc0 = fmaf(a.y, q0.y, acc0);
      acc0 = fmaf(a.z, q0.z, acc0); acc0 = fmaf(a.w, q0.w, acc0);
      acc1 = fmaf(a.x, q1.x, acc1); acc1 = fmaf(a.y, q1.y, acc1);
      acc1 = fmaf(a.z, q1.z, acc1); acc1 = fmaf(a.w, q1.w, acc1);
      acc2 = fmaf(a.x, q2.x, acc2); acc2 = fmaf(a.y, q2.y, acc2);
      acc2 = fmaf(a.z, q2.z, acc2); acc2 = fmaf(a.w, q2.w, acc2);
      acc3 = fmaf(a.x, q3.x, acc3); acc3 = fmaf(a.y, q3.y, acc3);
      acc3 = fmaf(a.z, q3.z, acc3); acc3 = fmaf(a.w, q3.w, acc3);
    }
  }

  {
    const float* b1e = b1 + e * 16 + og * 4;
    c_lds[m * 17 + og * 4 + 0] = acc0 + b1e[0];
    c_lds[m * 17 + og * 4 + 1] = acc1 + b1e[1];
    c_lds[m * 17 + og * 4 + 2] = acc2 + b1e[2];
    c_lds[m * 17 + og * 4 + 3] = acc3 + b1e[3];
  }
  __syncthreads();

  if (t < 64 && start + t < n) {
    const int token = tok_lds[t];
    const float* c = &c_lds[t * 17];
    const float xo = c[15];             // raw passthrough (l1x_out)
    float x[30];
#pragma unroll
    for (int j = 0; j < 15; ++j) {
      const float v = c[j];
      x[j]      = fminf(v * v * (255.0f / 256.0f), 1.0f);
      x[j + 15] = fminf(fmaxf(v, 0.0f), 1.0f);
    }
    const float* w2e = w2 + (size_t)e * 32 * 30;   // wave-uniform -> s_load
    const float* b2e = b2 + e * 32;
    const float* w3e = w3 + e * 32;
    float acc3v = b3[e];
#pragma unroll 1
    for (int o2 = 0; o2 < 32; ++o2) {
      float s = b2e[o2];
#pragma unroll
      for (int i = 0; i < 30; ++i) s = fmaf(x[i], w2e[o2 * 30 + i], s);
      s = fminf(fmaxf(s, 0.0f), 1.0f);
      acc3v = fmaf(s, w3e[o2], acc3v);
    }
    out[token] = acc3v + xo;
  }
}

extern "C" void kernel_launch(void* const* d_in, const int* in_sizes, int n_in,
                              void* d_out, int out_size, void* d_ws, size_t ws_size,
                              hipStream_t stream) {
  const float* xin = (const float*)d_in[0];   // expert_input (B, 2048)
  const float* rin = (const float*)d_in[1];   // router_input (B, 128)
  const float* rw  = (const float*)d_in[2];   // router_w (16, 128)
  const float* rb  = (const float*)d_in[3];   // router_b (16)
  const float* w1  = (const float*)d_in[4];   // l1_w (16, 16, 2048)
  const float* b1  = (const float*)d_in[5];   // l1_b (16, 16)
  const float* w2  = (const float*)d_in[6];   // l2_w (16, 32, 30)
  const float* b2  = (const float*)d_in[7];   // l2_b (16, 32)
  const float* w3  = (const float*)d_in[8];   // out_w (16, 1, 32)
  const float* b3  = (const float*)d_in[9];   // out_b (16, 1)
  float* out = (float*)d_out;

  int* counts = (int*)d_ws;                   // [16] (+pad to 64)
  int* perm   = counts + 64;                  // [16 * B_TOK]

  hipMemsetAsync(counts, 0, 64 * sizeof(int), stream);
  k_router<<<dim3(B_TOK / 64), 256, 0, stream>>>(rin, rw, rb, counts, perm);
  k_moe<<<dim3(B_TOK / 64, NEXP), 256, 0, stream>>>(xin, w1, b1, w2, b2, w3, b3,
                                                    counts, perm, out);
}